// Round 6
// baseline (168638.879 us; speedup 1.0000x reference)
//
#include <hip/hip_runtime.h>
#include <math.h>

#define B_ 32
#define T_ 512
#define D_ 1024
#define H_ 1024
#define L_ 4
#define NTICK (T_ + L_ - 1)   // 515
#define RP 17                 // reduce-buffer row pad (floats), coprime with 32 banks
#define SMEM_FLOATS (512 * RP) // 8704 floats = 34816 B; aliases staging tile xs[32][256]

// Spin on a RELAXED agent load, throttled by s_sleep(16) (~0.2 µs/poll) so the
// poll itself generates negligible fetch traffic. Caller issues ONE acquire
// fence after this returns. Short timeout + always-release (see below) means a
// straggler degrades to a wrong answer, never a hung GPU.
__device__ __forceinline__ bool waitCount(const unsigned int* p, unsigned int target) {
    int c = 0;
    while (__hip_atomic_load(p, __ATOMIC_RELAXED, __HIP_MEMORY_SCOPE_AGENT) < target) {
        __builtin_amdgcn_s_sleep(16);
        if (++c > 20000) return false;   // ~5 ms/tick worst case
    }
    return true;
}

// Persistent kernel. 256 blocks (1/CU), 512 threads. Block = (layer, 16-col slice).
// ROUND-6 CHANGE: weights are NOT register-pinned (that spilled: 128 VGPRs vs
// ~130 live -> 447 MB/tick of scratch writes, VALUBusy 3%). Each tile's 8
// weight floats are re-loaded from global per tick; per-XCD weight working set
// is 4 MB = L2-resident, so this is an L2 stream (~128 KB/CU/tick), and live
// registers drop to ~75 -> no spill.
__global__ __launch_bounds__(512) void lnn_persist(
    const float* __restrict__ x,      // [B][T][D]
    const float* __restrict__ W_in,   // [L][D][H]
    const float* __restrict__ b_in,   // [L][H]
    const float* __restrict__ W_h,    // [L][H][H]
    const float* __restrict__ b_h,    // [L][H]
    const float* __restrict__ tau,    // [L][H]
    float* __restrict__ buf0,         // [L][B][H] state, tick-parity 0
    float* __restrict__ buf1,         // [L][B][H] state, tick-parity 1
    unsigned int* __restrict__ count) // [NTICK] lockstep counters (zeroed per launch)
{
    const int tid   = threadIdx.x;
    const int layer = blockIdx.x >> 6;
    const int jbase = (blockIdx.x & 63) << 4;
    const int jj    = tid & 15;       // col within slice
    const int kslot = tid >> 4;       // 0..31
    const int jg    = jbase + jj;

    __shared__ __align__(16) float smem[SMEM_FLOATS];
    float (*xs)[256] = (float(*)[256])smem;

    const float* Wl_in = W_in + (size_t)layer * D_ * H_;
    const float* Wl_h  = W_h  + (size_t)layer * H_ * H_;

    const float bias = b_in[layer * H_ + jg] + b_h[layer * H_ + jg];
    const float tv   = tau[layer * H_ + jg];

    for (int tick = 0; tick < NTICK; ++tick) {
        if (tid == 0 && tick > 0) {
            (void)waitCount(&count[tick - 1], 256u);
            // ONE acquire per tick per block: invalidate stale caches so the
            // staging loads below see other blocks' tick-1 stores.
            __builtin_amdgcn_fence(__ATOMIC_ACQUIRE, "agent");
        }
        __syncthreads();   // all threads ordered after the acquire

        const int t = tick - layer;
        if (t >= 0 && t < T_) {
            const float* rb = (tick & 1) ? buf0 : buf1;   // state at t-1
            float*       wb = (tick & 1) ? buf1 : buf0;   // state at t

            const float* xsrc; size_t xstr;
            if (layer == 0) { xsrc = x + (size_t)t * D_;               xstr = (size_t)T_ * D_; }
            else            { xsrc = rb + (size_t)(layer - 1) * B_ * H_; xstr = H_; }
            const float* hsrc = rb + (size_t)layer * B_ * H_;

            float acc[32];
#pragma unroll
            for (int i = 0; i < 32; ++i) acc[i] = 0.f;

            const int kb = kslot << 3;
#pragma unroll
            for (int tile = 0; tile < 8; ++tile) {
                const float* src = (tile < 4) ? xsrc : hsrc;
                const size_t str = (tile < 4) ? xstr : (size_t)H_;
                const int    kof = (tile < 4) ? tile * 256 : tile * 256 - 1024;

                // Issue the tile's weight loads (strided dwords, L2-resident)
                // BEFORE the staging barrier so latency hides under it.
                const float* wp = (tile < 4)
                    ? Wl_in + (size_t)(tile * 256 + kb) * H_ + jg
                    : Wl_h  + (size_t)(tile * 256 - 1024 + kb) * H_ + jg;
                float wc[8];
#pragma unroll
                for (int i = 0; i < 8; ++i) wc[i] = wp[(size_t)i * H_];

                __syncthreads();   // LDS tile safe to overwrite
#pragma unroll
                for (int s4 = 0; s4 < 4; ++s4) {
                    const int e  = (s4 << 9) + tid;    // 0..2047 float4 index
                    const int r  = e >> 6;             // row 0..31
                    const int c4 = (e & 63) << 2;      // col 0..252
                    *(float4*)&xs[r][c4] = *(const float4*)&src[(size_t)r * str + kof + c4];
                }
                __syncthreads();
#pragma unroll
                for (int b = 0; b < 32; ++b) {
                    const float4 a0 = *(const float4*)&xs[b][kb];
                    const float4 a1 = *(const float4*)&xs[b][kb + 4];
                    acc[b] += a0.x * wc[0] + a0.y * wc[1]
                            + a0.z * wc[2] + a0.w * wc[3]
                            + a1.x * wc[4] + a1.y * wc[5]
                            + a1.z * wc[6] + a1.w * wc[7];
                }
            }

            // ---- two-phase k-reduction through padded LDS (union with xs) ----
            const float* rl = rb + (size_t)layer * B_ * H_;
            float*       wl = wb + (size_t)layer * B_ * H_;
#pragma unroll
            for (int p = 0; p < 2; ++p) {
                __syncthreads();   // previous LDS use complete
#pragma unroll
                for (int c = 0; c < 16; ++c)
                    smem[tid * RP + c] = acc[p * 16 + c];
                __syncthreads();
                if (tid < 256) {
                    const int c = tid >> 4;            // 0..15
                    const int b = c + p * 16;
                    float s = 0.f;
#pragma unroll
                    for (int ks = 0; ks < 32; ++ks)
                        s += smem[(jj + (ks << 4)) * RP + c];
                    const float dx   = tanhf(s + bias);
                    const float hold = rl[(size_t)b * H_ + jg];
                    const float hn   = hold + (dx - hold) / tv;
                    // relaxed agent store: lands at the coherence point, so the
                    // release-add below publishes it without extra flushing.
                    __hip_atomic_store(&wl[(size_t)b * H_ + jg], hn,
                                       __ATOMIC_RELAXED, __HIP_MEMORY_SCOPE_AGENT);
                }
            }
        }

        __syncthreads();   // all waves' stores issued & drained before release
        // ALWAYS increment — even after a wait timeout. A straggler must not
        // starve the other 255 blocks into per-tick timeouts (hang-by-cascade).
        if (tid == 0)
            __hip_atomic_fetch_add(&count[tick], 1u,
                                   __ATOMIC_RELEASE, __HIP_MEMORY_SCOPE_AGENT);
    }
}

// out[b][o] = sum_k h3[b][k] * W_out[k][o] + b_out[o]   (validated in round 0)
__global__ __launch_bounds__(256) void lnn_out(
    const float* __restrict__ H3,     // [B][H]
    const float* __restrict__ W_out,  // [H][O]
    const float* __restrict__ b_out,  // [O]
    float* __restrict__ out)          // [B][O]
{
    const int gid = blockIdx.x * 256 + threadIdx.x;  // 64 blocks -> 16384 threads
    const int jj  = gid & 1023;
    const int b2  = gid >> 10;                       // 0..15 -> rows b2, b2+16
    float acc0 = b_out[jj];
    float acc1 = b_out[jj];
    for (int k = 0; k < H_; ++k) {
        const float w = W_out[k * H_ + jj];
        acc0 += H3[b2 * H_ + k]        * w;
        acc1 += H3[(b2 + 16) * H_ + k] * w;
    }
    out[b2 * H_ + jj]        = acc0;
    out[(b2 + 16) * H_ + jj] = acc1;
}

extern "C" void kernel_launch(void* const* d_in, const int* in_sizes, int n_in,
                              void* d_out, int out_size, void* d_ws, size_t ws_size,
                              hipStream_t stream) {
    const float* x     = (const float*)d_in[0];
    const float* W_in  = (const float*)d_in[1];
    const float* b_in  = (const float*)d_in[2];
    const float* W_h   = (const float*)d_in[3];
    const float* b_h   = (const float*)d_in[4];
    const float* tau   = (const float*)d_in[5];
    const float* W_out = (const float*)d_in[6];
    const float* b_out = (const float*)d_in[7];

    const size_t stateElems = (size_t)L_ * B_ * H_;       // 131072 floats
    float* buf0 = (float*)d_ws;
    float* buf1 = buf0 + stateElems;
    unsigned int* count = (unsigned int*)(buf1 + stateElems);

    // zero state + lockstep counters (captured in the graph -> reset every replay)
    (void)hipMemsetAsync(d_ws, 0, 2 * stateElems * sizeof(float) + NTICK * sizeof(unsigned int), stream);

    lnn_persist<<<256, 512, 0, stream>>>(x, W_in, b_in, W_h, b_h, tau, buf0, buf1, count);

    // h3 at t=511 computed at tick 514 -> write buffer parity 514&1 = 0 -> buf0
    const float* H3 = buf0 + 3 * (B_ * H_);
    lnn_out<<<64, 256, 0, stream>>>(H3, W_out, b_out, (float*)d_out);
}

// Round 7
// 40527.451 us; speedup vs baseline: 4.1611x; 4.1611x over previous
//
#include <hip/hip_runtime.h>
#include <math.h>

#define B_ 32
#define T_ 512
#define D_ 1024
#define H_ 1024
#define L_ 4
#define NTICK (T_ + L_ - 1)    // 515
#define RP 17                  // reduce-buffer row pad (floats): stride 16*17=272 ≡ 16 mod 32 -> 2-way only
#define SMEM_FLOATS (512 * RP) // 8704 floats = 34816 B; aliases staging tile xs[32][256]

// Tick kernel (pipeline-skewed): at `tick`, layer l computes timestep t = tick - l.
// Grid 256 blocks = 4 layers x 64 col-slices(16). Block 512 thr = 16 jj x 32 kslot.
// Cross-layer/tick deps ride on kernel boundaries (HSA end-of-dispatch release):
// no atomics, no fences, normal cached loads/stores.
//
// __launch_bounds__(512, 2): 2 waves/SIMD = 1 block/CU -> up to 256 VGPR/thread.
// R2-R6 lesson: without this the compiler caps at 128 VGPR and spills acc[32]
// (~140 GB of scratch writes per run = the entire 300 us/tick).
__global__ __launch_bounds__(512, 2) void lnn_tick(
    const float* __restrict__ x,      // [B][T][D]
    const float* __restrict__ W_in,   // [L][D][H]
    const float* __restrict__ b_in,   // [L][H]
    const float* __restrict__ W_h,    // [L][H][H]
    const float* __restrict__ b_h,    // [L][H]
    const float* __restrict__ tau,    // [L][H]
    const float* __restrict__ Hread,  // [L][B][H] state at t-1
    float* __restrict__ Hwrite,       // [L][B][H] state at t
    int tick)
{
    const int tid   = threadIdx.x;
    const int layer = blockIdx.x >> 6;
    const int t     = tick - layer;
    if (t < 0 || t >= T_) return;     // uniform per block

    const int jbase = (blockIdx.x & 63) << 4;
    const int jj    = tid & 15;       // col within slice
    const int kslot = tid >> 4;       // 0..31
    const int jg    = jbase + jj;

    __shared__ __align__(16) float smem[SMEM_FLOATS];
    float (*xs)[256] = (float(*)[256])smem;

    const float* Wl_in = W_in + (size_t)layer * D_ * H_;
    const float* Wl_h  = W_h  + (size_t)layer * H_ * H_;
    const float* hrow  = Hread + (size_t)layer * B_ * H_;

    const float* xsrc; size_t xstr;
    if (layer == 0) { xsrc = x + (size_t)t * D_;                    xstr = (size_t)T_ * D_; }
    else            { xsrc = Hread + (size_t)(layer - 1) * B_ * H_; xstr = H_; }

    float acc[32];
#pragma unroll
    for (int i = 0; i < 32; ++i) acc[i] = 0.f;

    const int kb = kslot << 3;

    // K = 2048 (W_in over k<1024, then W_h). 8 tiles of 256.
    // unroll 1: keep wc[8]'s live range inside one iteration (anti-spill).
#pragma unroll 1
    for (int tile = 0; tile < 8; ++tile) {
        const float* src = (tile < 4) ? xsrc : hrow;
        const size_t str = (tile < 4) ? xstr : (size_t)H_;
        const int    kof = (tile & 3) << 8;

        // This tile's 8 weight floats (one col, 8 consecutive k): issue before
        // the staging barrier so L2 latency hides under it. Loaded exactly once
        // per block per tick -> weights stay L2-resident (4 MB/XCD working set).
        const float* wp = ((tile < 4) ? Wl_in : Wl_h) + (size_t)(kof + kb) * H_ + jg;
        float wc[8];
#pragma unroll
        for (int i = 0; i < 8; ++i) wc[i] = wp[(size_t)i * H_];

        __syncthreads();   // previous tile's consumers done
#pragma unroll
        for (int s4 = 0; s4 < 4; ++s4) {
            const int e  = (s4 << 9) + tid;    // 0..2047 float4 index
            const int r  = e >> 6;             // row 0..31
            const int c4 = (e & 63) << 2;      // col 0..252
            *(float4*)&xs[r][c4] = *(const float4*)&src[(size_t)r * str + kof + c4];
        }
        __syncthreads();

#pragma unroll
        for (int b = 0; b < 32; ++b) {
            const float4 a0 = *(const float4*)&xs[b][kb];
            const float4 a1 = *(const float4*)&xs[b][kb + 4];
            acc[b] += a0.x * wc[0] + a0.y * wc[1]
                    + a0.z * wc[2] + a0.w * wc[3]
                    + a1.x * wc[4] + a1.y * wc[5]
                    + a1.z * wc[6] + a1.w * wc[7];
        }
    }

    // ---- two-phase k-reduction through padded LDS (proven R0/R2/R5/R6) ----
    const float bias = b_in[layer * H_ + jg] + b_h[layer * H_ + jg];
    const float tv   = tau[layer * H_ + jg];
    float*      wl   = Hwrite + (size_t)layer * B_ * H_;

#pragma unroll 1
    for (int p = 0; p < 2; ++p) {
        __syncthreads();   // previous LDS use complete
#pragma unroll
        for (int c = 0; c < 16; ++c)
            smem[tid * RP + c] = acc[p * 16 + c];
        __syncthreads();
        if (tid < 256) {
            const int c = tid >> 4;            // 0..15
            const int b = c + p * 16;
            float s = 0.f;
#pragma unroll
            for (int ks = 0; ks < 32; ++ks)
                s += smem[(jj + (ks << 4)) * RP + c];
            const float dx   = tanhf(s + bias);
            const float hold = hrow[(size_t)b * H_ + jg];
            wl[(size_t)b * H_ + jg] = hold + (dx - hold) / tv;
        }
    }
}

// out[b][o] = sum_k h3[b][k] * W_out[k][o] + b_out[o]   (validated rounds 0-6)
__global__ __launch_bounds__(256) void lnn_out(
    const float* __restrict__ H3,     // [B][H]
    const float* __restrict__ W_out,  // [H][O]
    const float* __restrict__ b_out,  // [O]
    float* __restrict__ out)          // [B][O]
{
    const int gid = blockIdx.x * 256 + threadIdx.x;  // 64 blocks -> 16384 threads
    const int jj  = gid & 1023;
    const int b2  = gid >> 10;                       // 0..15 -> rows b2, b2+16
    float acc0 = b_out[jj];
    float acc1 = b_out[jj];
    for (int k = 0; k < H_; ++k) {
        const float w = W_out[k * H_ + jj];
        acc0 += H3[b2 * H_ + k]        * w;
        acc1 += H3[(b2 + 16) * H_ + k] * w;
    }
    out[b2 * H_ + jj]        = acc0;
    out[(b2 + 16) * H_ + jj] = acc1;
}

extern "C" void kernel_launch(void* const* d_in, const int* in_sizes, int n_in,
                              void* d_out, int out_size, void* d_ws, size_t ws_size,
                              hipStream_t stream) {
    const float* x     = (const float*)d_in[0];
    const float* W_in  = (const float*)d_in[1];
    const float* b_in  = (const float*)d_in[2];
    const float* W_h   = (const float*)d_in[3];
    const float* b_h   = (const float*)d_in[4];
    const float* tau   = (const float*)d_in[5];
    const float* W_out = (const float*)d_in[6];
    const float* b_out = (const float*)d_in[7];

    const size_t stateElems = (size_t)L_ * B_ * H_;       // 131072 floats
    float* buf0 = (float*)d_ws;
    float* buf1 = buf0 + stateElems;

    // zero both state buffers (captured in the graph -> re-zeroed every replay)
    (void)hipMemsetAsync(d_ws, 0, 2 * stateElems * sizeof(float), stream);

    for (int tick = 0; tick < NTICK; ++tick) {
        const float* Hr = buf0 + ((tick + 1) & 1) * stateElems;
        float*       Hw = buf0 + (tick & 1) * stateElems;
        lnn_tick<<<256, 512, 0, stream>>>(x, W_in, b_in, W_h, b_h, tau, Hr, Hw, tick);
    }
    // h3 at t=511 computed at tick 514 -> write parity 514&1 = 0 -> buf0
    const float* H3 = buf0 + 3 * (B_ * H_);
    lnn_out<<<64, 256, 0, stream>>>(H3, W_out, b_out, (float*)d_out);
    (void)buf1;
}